// Round 6
// baseline (156.348 us; speedup 1.0000x reference)
//
#include <hip/hip_runtime.h>
#include <math.h>

#define ZZ 128
#define CC 12
#define HH 512
#define NB 4096

typedef __attribute__((ext_vector_type(8))) short short8;
typedef __attribute__((ext_vector_type(4))) float f32x4;

__device__ __forceinline__ unsigned short f2bf(float x) {
    unsigned u = __builtin_bit_cast(unsigned, x);
    u += 0x7FFFu + ((u >> 16) & 1u);
    return (unsigned short)(u >> 16);
}
__device__ __forceinline__ float bf2f(unsigned short h) {
    unsigned u = ((unsigned)h) << 16;
    return __builtin_bit_cast(float, u);
}

// ---------------------------------------------------------------------------
// Prep: W1t/W2t transpose + bf16 hi/lo split ([N][K] layout); edge weights M.
// ---------------------------------------------------------------------------
__global__ __launch_bounds__(256) void k_prep(const float* __restrict__ W1,
                                              const float* __restrict__ W2,
                                              const int* __restrict__ adj,
                                              const int* __restrict__ tt,
                                              const float* __restrict__ w0p,
                                              short* __restrict__ W1tH, short* __restrict__ W1tL,
                                              short* __restrict__ W2tH, short* __restrict__ W2tL,
                                              float* __restrict__ M) {
    int bid = blockIdx.x, t = threadIdx.x;
    if (bid < 80) {
        __shared__ float T[64][65];
        const float* src; short *dH, *dL; int k0, n0, Krows;
        if (bid < 64) { src = W2; dH = W2tH; dL = W2tL; Krows = HH; k0 = (bid & 7) * 64; n0 = (bid >> 3) * 64; }
        else { int b = bid - 64; src = W1; dH = W1tH; dL = W1tL; Krows = ZZ; k0 = (b & 1) * 64; n0 = (b >> 1) * 64; }
#pragma unroll
        for (int it = 0; it < 16; ++it) {
            int idx = t + it * 256; int r = idx >> 6, c = idx & 63;
            T[r][c] = src[(size_t)(k0 + r) * HH + n0 + c];
        }
        __syncthreads();
#pragma unroll
        for (int it = 0; it < 16; ++it) {
            int idx = t + it * 256; int nl = idx >> 6, kl = idx & 63;
            float v = T[kl][nl];
            unsigned short h = f2bf(v);
            float lo = v - bf2f(h);
            size_t o = (size_t)(n0 + nl) * Krows + k0 + kl;
            dH[o] = (short)h; dL[o] = (short)f2bf(lo);
        }
    } else {
        float w0 = w0p[0];
#pragma unroll
        for (int it = 0; it < 64; ++it) {
            int e = t + it * 256;
            M[e] = adj[e] ? expf(-w0 * (float)tt[e]) : 0.f;
        }
    }
}

// ---------------------------------------------------------------------------
// next[b,i] = obs[b,i,:].w + sum_j act[b,j,i]*M[j,i]; bf16 hi/lo side output.
// 2048 blocks x 256 thr = 32 waves/CU: full-occupancy HBM stream.
// ---------------------------------------------------------------------------
__global__ __launch_bounds__(256) void k_next(const float* __restrict__ obs,
                                              const float* __restrict__ act,
                                              const float* __restrict__ M,
                                              const float* __restrict__ w0p,
                                              float* __restrict__ outn,
                                              short* __restrict__ nxtH,
                                              short* __restrict__ nxtL) {
    __shared__ float P[2][4][128];
    __shared__ float obsS[2][CC][128];
    __shared__ float wsh[16];
    int t = threadIdx.x;
    int b0 = blockIdx.x * 2;
    if (t < 16) wsh[t] = (t < CC) ? expf(-w0p[0] * (float)t) : 0.f;

    const float4* og = (const float4*)(obs + (size_t)b0 * ZZ * CC);
#pragma unroll
    for (int it = 0; it < 3; ++it) {
        int idx = t + it * 256;                 // [0, 768)
        float4 v = og[idx];
        int e = idx * 4;
        int bo = idx / 384;
        int rem = e - bo * 1536;
        int i = rem / CC;
        int c = rem - i * CC;                   // c in {0,4,8}
        obsS[bo][c + 0][i] = v.x;
        obsS[bo][c + 1][i] = v.y;
        obsS[bo][c + 2][i] = v.z;
        obsS[bo][c + 3][i] = v.w;
    }

    int i4 = t & 31, jg = (t >> 5) & 3, bo = t >> 7;
    const float* abase = act + (size_t)(b0 + bo) * ZZ * ZZ;
    float4 acc = make_float4(0.f, 0.f, 0.f, 0.f);
#pragma unroll 8
    for (int jj = 0; jj < 32; ++jj) {
        int j = jg * 32 + jj;
        float4 a = *(const float4*)&abase[j * ZZ + i4 * 4];
        float4 m = *(const float4*)&M[j * ZZ + i4 * 4];
        acc.x += a.x * m.x; acc.y += a.y * m.y; acc.z += a.z * m.z; acc.w += a.w * m.w;
    }
    *(float4*)&P[bo][jg][i4 * 4] = acc;
    __syncthreads();

    int i = t & 127, bo2 = t >> 7;
    int bb = b0 + bo2;
    float s = P[bo2][0][i] + P[bo2][1][i] + P[bo2][2][i] + P[bo2][3][i];
#pragma unroll
    for (int c = 0; c < CC; ++c) s += obsS[bo2][c][i] * wsh[c];
    outn[(size_t)bb * ZZ + i] = s;
    unsigned short h = f2bf(s);
    nxtH[bb * ZZ + i] = (short)h;
    nxtL[bb * ZZ + i] = (short)f2bf(s - bf2f(h));
}

// ---------------------------------------------------------------------------
// MLP: 256 blocks x 4 waves. Block owns 16 batch rows end-to-end; NO atomics:
// GEMM1 (wave = 128-col slice) -> X1 LDS; GEMM2 (wave = 128-col slice);
// per-wave relu-dot with Wf; LDS reduce across waves; single writer per row.
// ---------------------------------------------------------------------------
__global__ __launch_bounds__(256) void k_mlp(const short* __restrict__ nxtH,
                                             const short* __restrict__ nxtL,
                                             const short* __restrict__ W1tH,
                                             const short* __restrict__ W1tL,
                                             const short* __restrict__ W2tH,
                                             const short* __restrict__ W2tL,
                                             const float* __restrict__ b1,
                                             const float* __restrict__ b2,
                                             const float* __restrict__ Wf,
                                             const float* __restrict__ bfp,
                                             float* __restrict__ out) {
    __shared__ __align__(16) short AsH[16 * ZZ], AsL[16 * ZZ];     // 4+4 KB
    __shared__ __align__(16) short X1H[16 * HH], X1L[16 * HH];     // 16+16 KB
    __shared__ float red[4][16];
    int t = threadIdx.x;
    int b0 = blockIdx.x * 16;

    // stage A tile (16 x 128) from L2, swizzled
    {
        int row = t >> 4, ig = t & 15;
        int cs = (ig ^ (row & 7)) << 3;
        *(short8*)&AsH[row * ZZ + cs] = *(const short8*)&nxtH[(size_t)(b0 + row) * ZZ + ig * 8];
        *(short8*)&AsL[row * ZZ + cs] = *(const short8*)&nxtL[(size_t)(b0 + row) * ZZ + ig * 8];
    }
    __syncthreads();

    int lane = t & 63, wv = t >> 6;
    int l15 = lane & 15, l4 = lane >> 4;
    int nwb = wv * 128;                          // this wave's N-slice [nwb, nwb+128)

    // ---------------- GEMM1: x1 = relu(next @ W1t^T + b1) ----------------
    f32x4 acc[8] = {};
    float b1c[8];
#pragma unroll
    for (int nf = 0; nf < 8; ++nf) b1c[nf] = b1[nwb + nf * 16 + l15];
#pragma unroll
    for (int s = 0; s < 4; ++s) {
        int chunk = s * 4 + l4;                  // 0..15 (K=128)
        int aaddr = l15 * ZZ + ((chunk ^ (l15 & 7)) << 3);
        short8 ah = *(const short8*)&AsH[aaddr];
        short8 al = *(const short8*)&AsL[aaddr];
        short8 bh[8], bl[8];
#pragma unroll
        for (int nf = 0; nf < 8; ++nf) {
            int n = nwb + nf * 16 + l15;
            bh[nf] = *(const short8*)&W1tH[(size_t)n * ZZ + chunk * 8];
            bl[nf] = *(const short8*)&W1tL[(size_t)n * ZZ + chunk * 8];
        }
#pragma unroll
        for (int nf = 0; nf < 8; ++nf) {
            acc[nf] = __builtin_amdgcn_mfma_f32_16x16x32_bf16(ah, bh[nf], acc[nf], 0, 0, 0);
            acc[nf] = __builtin_amdgcn_mfma_f32_16x16x32_bf16(ah, bl[nf], acc[nf], 0, 0, 0);
            acc[nf] = __builtin_amdgcn_mfma_f32_16x16x32_bf16(al, bh[nf], acc[nf], 0, 0, 0);
        }
    }
#pragma unroll
    for (int nf = 0; nf < 8; ++nf) {
        int col = nwb + nf * 16 + l15;
        int chunk2 = col >> 3, cw = col & 7;
#pragma unroll
        for (int r = 0; r < 4; ++r) {
            int row = l4 * 4 + r;
            float v = fmaxf(acc[nf][r] + b1c[nf], 0.f);
            unsigned short h = f2bf(v);
            int addr = row * HH + ((chunk2 ^ (row & 7)) << 3) + cw;
            X1H[addr] = (short)h;
            X1L[addr] = (short)f2bf(v - bf2f(h));
        }
    }
    __syncthreads();

    // ---------------- GEMM2: x2 = relu(x1 @ W2t^T + b2), 128 cols/wave -----
    f32x4 acc2[8] = {};
#pragma unroll 2
    for (int ks = 0; ks < 16; ++ks) {
        int chunk = ks * 4 + l4;                 // 0..63 (K=512)
        int aaddr = l15 * HH + ((chunk ^ (l15 & 7)) << 3);
        short8 ah = *(const short8*)&X1H[aaddr];
        short8 al = *(const short8*)&X1L[aaddr];
        short8 bh[8], bl[8];
#pragma unroll
        for (int nf = 0; nf < 8; ++nf) {
            int n = nwb + nf * 16 + l15;
            bh[nf] = *(const short8*)&W2tH[(size_t)n * HH + chunk * 8];
            bl[nf] = *(const short8*)&W2tL[(size_t)n * HH + chunk * 8];
        }
#pragma unroll
        for (int nf = 0; nf < 8; ++nf) {
            acc2[nf] = __builtin_amdgcn_mfma_f32_16x16x32_bf16(ah, bh[nf], acc2[nf], 0, 0, 0);
            acc2[nf] = __builtin_amdgcn_mfma_f32_16x16x32_bf16(ah, bl[nf], acc2[nf], 0, 0, 0);
            acc2[nf] = __builtin_amdgcn_mfma_f32_16x16x32_bf16(al, bh[nf], acc2[nf], 0, 0, 0);
        }
    }

    // ---------------- out[b] = relu(x2)·Wf + bf (LDS reduce, no atomics) ---
    float b2c[8], wfc[8];
#pragma unroll
    for (int nf = 0; nf < 8; ++nf) {
        int col = nwb + nf * 16 + l15;
        b2c[nf] = b2[col];
        wfc[nf] = Wf[col];
    }
    float p[4];
#pragma unroll
    for (int r = 0; r < 4; ++r) {
        float s = 0.f;
#pragma unroll
        for (int nf = 0; nf < 8; ++nf)
            s += fmaxf(acc2[nf][r] + b2c[nf], 0.f) * wfc[nf];
        s += __shfl_xor(s, 1);
        s += __shfl_xor(s, 2);
        s += __shfl_xor(s, 4);
        s += __shfl_xor(s, 8);
        p[r] = s;
    }
    if (l15 == 0) {
#pragma unroll
        for (int r = 0; r < 4; ++r) red[wv][l4 * 4 + r] = p[r];
    }
    __syncthreads();
    if (t < 16)
        out[b0 + t] = red[0][t] + red[1][t] + red[2][t] + red[3][t] + bfp[0];
}

extern "C" void kernel_launch(void* const* d_in, const int* in_sizes, int n_in,
                              void* d_out, int out_size, void* d_ws, size_t ws_size,
                              hipStream_t stream) {
    const float* obs = (const float*)d_in[0];
    const float* act = (const float*)d_in[1];
    const float* w0  = (const float*)d_in[2];
    const float* W1  = (const float*)d_in[3];
    const float* b1  = (const float*)d_in[4];
    const float* W2  = (const float*)d_in[5];
    const float* b2  = (const float*)d_in[6];
    const float* Wf  = (const float*)d_in[7];
    const float* bf  = (const float*)d_in[8];
    const int* adj   = (const int*)d_in[9];
    const int* tt    = (const int*)d_in[10];

    float* out = (float*)d_out;               // [0:NB) symbolic_val, [NB:) next_state
    float* outn = out + NB;

    char* base = (char*)d_ws;
    float* M    = (float*)base;                               // 64 KB
    short* nxtH = (short*)(base + (1u << 16));                // 1 MB
    short* nxtL = (short*)(base + (1u << 16) + (1u << 20));
    char* p = base + (1u << 16) + (2u << 20);
    short* W1tH = (short*)p;  p += (size_t)HH * ZZ * 2;       // 128 KB each
    short* W1tL = (short*)p;  p += (size_t)HH * ZZ * 2;
    short* W2tH = (short*)p;  p += (size_t)HH * HH * 2;       // 512 KB each
    short* W2tL = (short*)p;

    k_prep<<<81, 256, 0, stream>>>(W1, W2, adj, tt, w0,
                                   W1tH, W1tL, W2tH, W2tL, M);
    k_next<<<NB / 2, 256, 0, stream>>>(obs, act, M, w0, outn, nxtH, nxtL);
    k_mlp<<<NB / 16, 256, 0, stream>>>(nxtH, nxtL, W1tH, W1tL, W2tH, W2tL,
                                       b1, b2, Wf, bf, out);
}

// Round 7
// 146.985 us; speedup vs baseline: 1.0637x; 1.0637x over previous
//
#include <hip/hip_runtime.h>
#include <math.h>

#define ZZ 128
#define CC 12
#define HH 512
#define NB 4096

typedef __attribute__((ext_vector_type(8))) short short8;
typedef __attribute__((ext_vector_type(4))) float f32x4;

__device__ __forceinline__ unsigned short f2bf(float x) {
    unsigned u = __builtin_bit_cast(unsigned, x);
    u += 0x7FFFu + ((u >> 16) & 1u);
    return (unsigned short)(u >> 16);
}
__device__ __forceinline__ float bf2f(unsigned short h) {
    unsigned u = ((unsigned)h) << 16;
    return __builtin_bit_cast(float, u);
}

// Fragment-interleaved weight layout: element (n,k) ->
//   ((n>>4)*KCH + (k>>3))*128 + (n&15)*8 + (k&7)      [KCH = K/8 chunks]
// A wave's fragment load (16 n x 8 k, 4 chunk-groups) is then one
// contiguous 1KB read: offset = l4*256B + l15*16B. Coalescing fix for the
// 64-transactions-per-load pattern that killed rounds 2-6.

// ---------------------------------------------------------------------------
// Prep: W1p/W2p fragment-interleaved bf16 hi/lo; edge weights M.
// ---------------------------------------------------------------------------
__global__ __launch_bounds__(256) void k_prep(const float* __restrict__ W1,
                                              const float* __restrict__ W2,
                                              const int* __restrict__ adj,
                                              const int* __restrict__ tt,
                                              const float* __restrict__ w0p,
                                              short* __restrict__ W1pH, short* __restrict__ W1pL,
                                              short* __restrict__ W2pH, short* __restrict__ W2pL,
                                              float* __restrict__ M) {
    int bid = blockIdx.x, t = threadIdx.x;
    if (bid < 80) {
        __shared__ float T[64][65];
        const float* src; short *dH, *dL; int k0, n0, kch;
        if (bid < 64) { src = W2; dH = W2pH; dL = W2pL; kch = HH / 8; k0 = (bid & 7) * 64; n0 = (bid >> 3) * 64; }
        else { int b = bid - 64; src = W1; dH = W1pH; dL = W1pL; kch = ZZ / 8; k0 = (b & 1) * 64; n0 = (b >> 1) * 64; }
#pragma unroll
        for (int it = 0; it < 16; ++it) {
            int idx = t + it * 256; int r = idx >> 6, c = idx & 63;
            T[r][c] = src[(size_t)(k0 + r) * HH + n0 + c];
        }
        __syncthreads();
#pragma unroll
        for (int it = 0; it < 16; ++it) {
            int idx = t + it * 256; int nl = idx >> 6, kl = idx & 63;
            float v = T[kl][nl];
            unsigned short h = f2bf(v);
            float lo = v - bf2f(h);
            int n = n0 + nl, k = k0 + kl;
            size_t o = ((size_t)((n >> 4) * kch + (k >> 3)) << 7) + ((n & 15) << 3) + (k & 7);
            dH[o] = (short)h; dL[o] = (short)f2bf(lo);
        }
    } else {
        float w0 = w0p[0];
#pragma unroll
        for (int it = 0; it < 64; ++it) {
            int e = t + it * 256;
            M[e] = adj[e] ? expf(-w0 * (float)tt[e]) : 0.f;
        }
    }
}

// ---------------------------------------------------------------------------
// next[b,i] = obs[b,i,:].w + sum_j act[b,j,i]*M[j,i]; bf16 hi/lo side output.
// 2048 blocks x 256 thr = 32 waves/CU: full-occupancy HBM stream.
// ---------------------------------------------------------------------------
__global__ __launch_bounds__(256) void k_next(const float* __restrict__ obs,
                                              const float* __restrict__ act,
                                              const float* __restrict__ M,
                                              const float* __restrict__ w0p,
                                              float* __restrict__ outn,
                                              short* __restrict__ nxtH,
                                              short* __restrict__ nxtL) {
    __shared__ float P[2][4][128];
    __shared__ float obsS[2][CC][128];
    __shared__ float wsh[16];
    int t = threadIdx.x;
    int b0 = blockIdx.x * 2;
    if (t < 16) wsh[t] = (t < CC) ? expf(-w0p[0] * (float)t) : 0.f;

    const float4* og = (const float4*)(obs + (size_t)b0 * ZZ * CC);
#pragma unroll
    for (int it = 0; it < 3; ++it) {
        int idx = t + it * 256;                 // [0, 768)
        float4 v = og[idx];
        int e = idx * 4;
        int bo = idx / 384;
        int rem = e - bo * 1536;
        int i = rem / CC;
        int c = rem - i * CC;                   // c in {0,4,8}
        obsS[bo][c + 0][i] = v.x;
        obsS[bo][c + 1][i] = v.y;
        obsS[bo][c + 2][i] = v.z;
        obsS[bo][c + 3][i] = v.w;
    }

    int i4 = t & 31, jg = (t >> 5) & 3, bo = t >> 7;
    const float* abase = act + (size_t)(b0 + bo) * ZZ * ZZ;
    float4 acc = make_float4(0.f, 0.f, 0.f, 0.f);
#pragma unroll 8
    for (int jj = 0; jj < 32; ++jj) {
        int j = jg * 32 + jj;
        float4 a = *(const float4*)&abase[j * ZZ + i4 * 4];
        float4 m = *(const float4*)&M[j * ZZ + i4 * 4];
        acc.x += a.x * m.x; acc.y += a.y * m.y; acc.z += a.z * m.z; acc.w += a.w * m.w;
    }
    *(float4*)&P[bo][jg][i4 * 4] = acc;
    __syncthreads();

    int i = t & 127, bo2 = t >> 7;
    int bb = b0 + bo2;
    float s = P[bo2][0][i] + P[bo2][1][i] + P[bo2][2][i] + P[bo2][3][i];
#pragma unroll
    for (int c = 0; c < CC; ++c) s += obsS[bo2][c][i] * wsh[c];
    outn[(size_t)bb * ZZ + i] = s;
    unsigned short h = f2bf(s);
    nxtH[bb * ZZ + i] = (short)h;
    nxtL[bb * ZZ + i] = (short)f2bf(s - bf2f(h));
}

// ---------------------------------------------------------------------------
// MLP: 256 blocks x 4 waves. Block owns 16 batch rows end-to-end; no atomics.
// B-fragment loads are now contiguous 1KB wave-reads (fragment-interleaved W).
// ---------------------------------------------------------------------------
__global__ __launch_bounds__(256) void k_mlp(const short* __restrict__ nxtH,
                                             const short* __restrict__ nxtL,
                                             const short* __restrict__ W1pH,
                                             const short* __restrict__ W1pL,
                                             const short* __restrict__ W2pH,
                                             const short* __restrict__ W2pL,
                                             const float* __restrict__ b1,
                                             const float* __restrict__ b2,
                                             const float* __restrict__ Wf,
                                             const float* __restrict__ bfp,
                                             float* __restrict__ out) {
    __shared__ __align__(16) short AsH[16 * ZZ], AsL[16 * ZZ];     // 4+4 KB
    __shared__ __align__(16) short X1H[16 * HH], X1L[16 * HH];     // 16+16 KB
    __shared__ float red[4][16];
    int t = threadIdx.x;
    int b0 = blockIdx.x * 16;

    // stage A tile (16 x 128) from L2, swizzled
    {
        int row = t >> 4, ig = t & 15;
        int cs = (ig ^ (row & 7)) << 3;
        *(short8*)&AsH[row * ZZ + cs] = *(const short8*)&nxtH[(size_t)(b0 + row) * ZZ + ig * 8];
        *(short8*)&AsL[row * ZZ + cs] = *(const short8*)&nxtL[(size_t)(b0 + row) * ZZ + ig * 8];
    }
    __syncthreads();

    int lane = t & 63, wv = t >> 6;
    int l15 = lane & 15, l4 = lane >> 4;
    int nwb = wv * 128;                          // this wave's N-slice [nwb, nwb+128)

    // ---------------- GEMM1: x1 = relu(next @ W1^T + b1) ----------------
    f32x4 acc[8] = {};
    float b1c[8];
#pragma unroll
    for (int nf = 0; nf < 8; ++nf) b1c[nf] = b1[nwb + nf * 16 + l15];
#pragma unroll
    for (int s = 0; s < 4; ++s) {
        int chunk = s * 4 + l4;                  // 0..15 (K=128)
        int aaddr = l15 * ZZ + ((chunk ^ (l15 & 7)) << 3);
        short8 ah = *(const short8*)&AsH[aaddr];
        short8 al = *(const short8*)&AsL[aaddr];
        short8 bh[8], bl[8];
#pragma unroll
        for (int nf = 0; nf < 8; ++nf) {
            size_t o = ((size_t)((wv * 8 + nf) * 16 + chunk) << 7) + (l15 << 3);
            bh[nf] = *(const short8*)&W1pH[o];
            bl[nf] = *(const short8*)&W1pL[o];
        }
#pragma unroll
        for (int nf = 0; nf < 8; ++nf) {
            acc[nf] = __builtin_amdgcn_mfma_f32_16x16x32_bf16(ah, bh[nf], acc[nf], 0, 0, 0);
            acc[nf] = __builtin_amdgcn_mfma_f32_16x16x32_bf16(ah, bl[nf], acc[nf], 0, 0, 0);
            acc[nf] = __builtin_amdgcn_mfma_f32_16x16x32_bf16(al, bh[nf], acc[nf], 0, 0, 0);
        }
    }
#pragma unroll
    for (int nf = 0; nf < 8; ++nf) {
        int col = nwb + nf * 16 + l15;
        int chunk2 = col >> 3, cw = col & 7;
#pragma unroll
        for (int r = 0; r < 4; ++r) {
            int row = l4 * 4 + r;
            float v = fmaxf(acc[nf][r] + b1c[nf], 0.f);
            unsigned short h = f2bf(v);
            int addr = row * HH + ((chunk2 ^ (row & 7)) << 3) + cw;
            X1H[addr] = (short)h;
            X1L[addr] = (short)f2bf(v - bf2f(h));
        }
    }
    __syncthreads();

    // ---------------- GEMM2: x2 = relu(x1 @ W2^T + b2), 128 cols/wave -----
    f32x4 acc2[8] = {};
#pragma unroll 2
    for (int ks = 0; ks < 16; ++ks) {
        int chunk = ks * 4 + l4;                 // 0..63 (K=512)
        int aaddr = l15 * HH + ((chunk ^ (l15 & 7)) << 3);
        short8 ah = *(const short8*)&X1H[aaddr];
        short8 al = *(const short8*)&X1L[aaddr];
        short8 bh[8], bl[8];
#pragma unroll
        for (int nf = 0; nf < 8; ++nf) {
            size_t o = ((size_t)((wv * 8 + nf) * 64 + chunk) << 7) + (l15 << 3);
            bh[nf] = *(const short8*)&W2pH[o];
            bl[nf] = *(const short8*)&W2pL[o];
        }
#pragma unroll
        for (int nf = 0; nf < 8; ++nf) {
            acc2[nf] = __builtin_amdgcn_mfma_f32_16x16x32_bf16(ah, bh[nf], acc2[nf], 0, 0, 0);
            acc2[nf] = __builtin_amdgcn_mfma_f32_16x16x32_bf16(ah, bl[nf], acc2[nf], 0, 0, 0);
            acc2[nf] = __builtin_amdgcn_mfma_f32_16x16x32_bf16(al, bh[nf], acc2[nf], 0, 0, 0);
        }
    }

    // ---------------- out[b] = relu(x2)·Wf + bf (LDS reduce, no atomics) ---
    float b2c[8], wfc[8];
#pragma unroll
    for (int nf = 0; nf < 8; ++nf) {
        int col = nwb + nf * 16 + l15;
        b2c[nf] = b2[col];
        wfc[nf] = Wf[col];
    }
    float p[4];
#pragma unroll
    for (int r = 0; r < 4; ++r) {
        float s = 0.f;
#pragma unroll
        for (int nf = 0; nf < 8; ++nf)
            s += fmaxf(acc2[nf][r] + b2c[nf], 0.f) * wfc[nf];
        s += __shfl_xor(s, 1);
        s += __shfl_xor(s, 2);
        s += __shfl_xor(s, 4);
        s += __shfl_xor(s, 8);
        p[r] = s;
    }
    if (l15 == 0) {
#pragma unroll
        for (int r = 0; r < 4; ++r) red[wv][l4 * 4 + r] = p[r];
    }
    __syncthreads();
    if (t < 16)
        out[b0 + t] = red[0][t] + red[1][t] + red[2][t] + red[3][t] + bfp[0];
}

extern "C" void kernel_launch(void* const* d_in, const int* in_sizes, int n_in,
                              void* d_out, int out_size, void* d_ws, size_t ws_size,
                              hipStream_t stream) {
    const float* obs = (const float*)d_in[0];
    const float* act = (const float*)d_in[1];
    const float* w0  = (const float*)d_in[2];
    const float* W1  = (const float*)d_in[3];
    const float* b1  = (const float*)d_in[4];
    const float* W2  = (const float*)d_in[5];
    const float* b2  = (const float*)d_in[6];
    const float* Wf  = (const float*)d_in[7];
    const float* bf  = (const float*)d_in[8];
    const int* adj   = (const int*)d_in[9];
    const int* tt    = (const int*)d_in[10];

    float* out = (float*)d_out;               // [0:NB) symbolic_val, [NB:) next_state
    float* outn = out + NB;

    char* base = (char*)d_ws;
    float* M    = (float*)base;                               // 64 KB
    short* nxtH = (short*)(base + (1u << 16));                // 1 MB
    short* nxtL = (short*)(base + (1u << 16) + (1u << 20));
    char* p = base + (1u << 16) + (2u << 20);
    short* W1pH = (short*)p;  p += (size_t)HH * ZZ * 2;       // 128 KB each
    short* W1pL = (short*)p;  p += (size_t)HH * ZZ * 2;
    short* W2pH = (short*)p;  p += (size_t)HH * HH * 2;       // 512 KB each
    short* W2pL = (short*)p;

    k_prep<<<81, 256, 0, stream>>>(W1, W2, adj, tt, w0,
                                   W1pH, W1pL, W2pH, W2pL, M);
    k_next<<<NB / 2, 256, 0, stream>>>(obs, act, M, w0, outn, nxtH, nxtL);
    k_mlp<<<NB / 16, 256, 0, stream>>>(nxtH, nxtL, W1pH, W1pL, W2pH, W2pL,
                                       b1, b2, Wf, bf, out);
}

// Round 8
// 137.761 us; speedup vs baseline: 1.1349x; 1.0670x over previous
//
#include <hip/hip_runtime.h>
#include <math.h>

#define ZZ 128
#define CC 12
#define HH 512
#define NB 4096

typedef __attribute__((ext_vector_type(8))) short short8;
typedef __attribute__((ext_vector_type(4))) float f32x4;

__device__ __forceinline__ unsigned short f2bf(float x) {
    unsigned u = __builtin_bit_cast(unsigned, x);
    u += 0x7FFFu + ((u >> 16) & 1u);
    return (unsigned short)(u >> 16);
}
__device__ __forceinline__ float bf2f(unsigned short h) {
    unsigned u = ((unsigned)h) << 16;
    return __builtin_bit_cast(float, u);
}

// Fragment-interleaved weight layout: element (n,k) ->
//   ((n>>4)*KCH + (k>>3))*128 + (n&15)*8 + (k&7)      [KCH = K/8]
// One wave fragment load = contiguous 1KB: offset l4*256B + l15*16B.

// ---------------------------------------------------------------------------
// Prep: W1p/W2p fragment-interleaved bf16 hi/lo; edge weights M.
// ---------------------------------------------------------------------------
__global__ __launch_bounds__(256) void k_prep(const float* __restrict__ W1,
                                              const float* __restrict__ W2,
                                              const int* __restrict__ adj,
                                              const int* __restrict__ tt,
                                              const float* __restrict__ w0p,
                                              short* __restrict__ W1pH, short* __restrict__ W1pL,
                                              short* __restrict__ W2pH, short* __restrict__ W2pL,
                                              float* __restrict__ M) {
    int bid = blockIdx.x, t = threadIdx.x;
    if (bid < 80) {
        __shared__ float T[64][65];
        const float* src; short *dH, *dL; int k0, n0, kch;
        if (bid < 64) { src = W2; dH = W2pH; dL = W2pL; kch = HH / 8; k0 = (bid & 7) * 64; n0 = (bid >> 3) * 64; }
        else { int b = bid - 64; src = W1; dH = W1pH; dL = W1pL; kch = ZZ / 8; k0 = (b & 1) * 64; n0 = (b >> 1) * 64; }
#pragma unroll
        for (int it = 0; it < 16; ++it) {
            int idx = t + it * 256; int r = idx >> 6, c = idx & 63;
            T[r][c] = src[(size_t)(k0 + r) * HH + n0 + c];
        }
        __syncthreads();
#pragma unroll
        for (int it = 0; it < 16; ++it) {
            int idx = t + it * 256; int nl = idx >> 6, kl = idx & 63;
            float v = T[kl][nl];
            unsigned short h = f2bf(v);
            float lo = v - bf2f(h);
            int n = n0 + nl, k = k0 + kl;
            size_t o = ((size_t)((n >> 4) * kch + (k >> 3)) << 7) + ((n & 15) << 3) + (k & 7);
            dH[o] = (short)h; dL[o] = (short)f2bf(lo);
        }
    } else {
        float w0 = w0p[0];
#pragma unroll
        for (int it = 0; it < 64; ++it) {
            int e = t + it * 256;
            M[e] = adj[e] ? expf(-w0 * (float)tt[e]) : 0.f;
        }
    }
}

// ---------------------------------------------------------------------------
// next[b,i] = obs[b,i,:].w + sum_j act[b,j,i]*M[j,i]; bf16 hi/lo side output.
// 2048 blocks x 256 thr = 32 waves/CU: full-occupancy HBM stream.
// ---------------------------------------------------------------------------
__global__ __launch_bounds__(256) void k_next(const float* __restrict__ obs,
                                              const float* __restrict__ act,
                                              const float* __restrict__ M,
                                              const float* __restrict__ w0p,
                                              float* __restrict__ outn,
                                              short* __restrict__ nxtH,
                                              short* __restrict__ nxtL) {
    __shared__ float P[2][4][128];
    __shared__ float obsS[2][CC][128];
    __shared__ float wsh[16];
    int t = threadIdx.x;
    int b0 = blockIdx.x * 2;
    if (t < 16) wsh[t] = (t < CC) ? expf(-w0p[0] * (float)t) : 0.f;

    const float4* og = (const float4*)(obs + (size_t)b0 * ZZ * CC);
#pragma unroll
    for (int it = 0; it < 3; ++it) {
        int idx = t + it * 256;                 // [0, 768)
        float4 v = og[idx];
        int e = idx * 4;
        int bo = idx / 384;
        int rem = e - bo * 1536;
        int i = rem / CC;
        int c = rem - i * CC;                   // c in {0,4,8}
        obsS[bo][c + 0][i] = v.x;
        obsS[bo][c + 1][i] = v.y;
        obsS[bo][c + 2][i] = v.z;
        obsS[bo][c + 3][i] = v.w;
    }

    int i4 = t & 31, jg = (t >> 5) & 3, bo = t >> 7;
    const float* abase = act + (size_t)(b0 + bo) * ZZ * ZZ;
    float4 acc = make_float4(0.f, 0.f, 0.f, 0.f);
#pragma unroll 8
    for (int jj = 0; jj < 32; ++jj) {
        int j = jg * 32 + jj;
        float4 a = *(const float4*)&abase[j * ZZ + i4 * 4];
        float4 m = *(const float4*)&M[j * ZZ + i4 * 4];
        acc.x += a.x * m.x; acc.y += a.y * m.y; acc.z += a.z * m.z; acc.w += a.w * m.w;
    }
    *(float4*)&P[bo][jg][i4 * 4] = acc;
    __syncthreads();

    int i = t & 127, bo2 = t >> 7;
    int bb = b0 + bo2;
    float s = P[bo2][0][i] + P[bo2][1][i] + P[bo2][2][i] + P[bo2][3][i];
#pragma unroll
    for (int c = 0; c < CC; ++c) s += obsS[bo2][c][i] * wsh[c];
    outn[(size_t)bb * ZZ + i] = s;
    unsigned short h = f2bf(s);
    nxtH[bb * ZZ + i] = (short)h;
    nxtL[bb * ZZ + i] = (short)f2bf(s - bf2f(h));
}

// ---------------------------------------------------------------------------
// MLP: grid 1024 = (rowgroup 0..255) x (col-slice 0..3); 256 thr = 4 waves;
// 4 blocks/CU -> 4 waves/SIMD. GEMM1 (full 512 cols, recomputed per slice,
// weights L2-hot) -> X1 LDS; GEMM2 wave = 32 cols of this block's 128-col
// slice (only bh[2]/bl[2] live -> low VGPR, all loads in flight).
// Partial Wf-dots go to ws; k_fin combines. No atomics anywhere.
// ---------------------------------------------------------------------------
__global__ __launch_bounds__(256, 2) void k_mlp(const short* __restrict__ nxtH,
                                                const short* __restrict__ nxtL,
                                                const short* __restrict__ W1pH,
                                                const short* __restrict__ W1pL,
                                                const short* __restrict__ W2pH,
                                                const short* __restrict__ W2pL,
                                                const float* __restrict__ b1,
                                                const float* __restrict__ b2,
                                                const float* __restrict__ Wf,
                                                float* __restrict__ part) {
    __shared__ __align__(16) short AsH[16 * ZZ], AsL[16 * ZZ];     // 4+4 KB
    __shared__ __align__(16) short X1H[16 * HH], X1L[16 * HH];     // 16+16 KB
    int t = threadIdx.x;
    int rg = blockIdx.x >> 2, sl = blockIdx.x & 3;
    int b0 = rg * 16;

    // stage A (16x128) swizzled: (row, chunk) -> As[row*128 + ((chunk^row)<<3)]
    {
        int row = t >> 4, ig = t & 15;
        int cs = (ig ^ row) << 3;
        *(short8*)&AsH[row * ZZ + cs] = *(const short8*)&nxtH[(size_t)(b0 + row) * ZZ + ig * 8];
        *(short8*)&AsL[row * ZZ + cs] = *(const short8*)&nxtL[(size_t)(b0 + row) * ZZ + ig * 8];
    }
    __syncthreads();

    int lane = t & 63, wv = t >> 6;
    int l15 = lane & 15, l4 = lane >> 4;

    // ---------------- GEMM1: x1 = relu(next @ W1^T + b1), wave = 128 cols ---
    int nwb = wv * 128;
    f32x4 acc[8] = {};
#pragma unroll
    for (int s = 0; s < 4; ++s) {
        int chunk = s * 4 + l4;                  // 0..15 (K=128)
        int aaddr = l15 * ZZ + ((chunk ^ l15) << 3);
        short8 ah = *(const short8*)&AsH[aaddr];
        short8 al = *(const short8*)&AsL[aaddr];
#pragma unroll
        for (int nfh = 0; nfh < 2; ++nfh) {      // nf blocked by 4: low VGPR
            short8 bh[4], bl[4];
#pragma unroll
            for (int q = 0; q < 4; ++q) {
                int nf = nfh * 4 + q;
                size_t o = ((size_t)((wv * 8 + nf) * 16 + chunk) << 7) + (l15 << 3);
                bh[q] = *(const short8*)&W1pH[o];
                bl[q] = *(const short8*)&W1pL[o];
            }
#pragma unroll
            for (int q = 0; q < 4; ++q) {
                int nf = nfh * 4 + q;
                acc[nf] = __builtin_amdgcn_mfma_f32_16x16x32_bf16(ah, bh[q], acc[nf], 0, 0, 0);
                acc[nf] = __builtin_amdgcn_mfma_f32_16x16x32_bf16(ah, bl[q], acc[nf], 0, 0, 0);
                acc[nf] = __builtin_amdgcn_mfma_f32_16x16x32_bf16(al, bh[q], acc[nf], 0, 0, 0);
            }
        }
    }
#pragma unroll
    for (int nf = 0; nf < 8; ++nf) {
        int col = nwb + nf * 16 + l15;
        float bv = b1[col];
        int chunk2 = col >> 3, cw = col & 7;
#pragma unroll
        for (int r = 0; r < 4; ++r) {
            int row = l4 * 4 + r;
            float v = fmaxf(acc[nf][r] + bv, 0.f);
            unsigned short h = f2bf(v);
            int addr = row * HH + ((chunk2 ^ row) << 3) + cw;
            X1H[addr] = (short)h;
            X1L[addr] = (short)f2bf(v - bf2f(h));
        }
    }
    __syncthreads();

    // ---------------- GEMM2: wave = 32 cols of slice sl --------------------
    int ncb = sl * 128 + wv * 32;
    f32x4 acc2[2] = {};
#pragma unroll
    for (int ks = 0; ks < 16; ++ks) {
        int chunk = ks * 4 + l4;                 // 0..63 (K=512)
        int aaddr = l15 * HH + ((chunk ^ l15) << 3);
        short8 ah = *(const short8*)&X1H[aaddr];
        short8 al = *(const short8*)&X1L[aaddr];
        short8 bh[2], bl[2];
#pragma unroll
        for (int nf = 0; nf < 2; ++nf) {
            size_t o = ((size_t)(((ncb >> 4) + nf) * 64 + chunk) << 7) + (l15 << 3);
            bh[nf] = *(const short8*)&W2pH[o];
            bl[nf] = *(const short8*)&W2pL[o];
        }
#pragma unroll
        for (int nf = 0; nf < 2; ++nf) {
            acc2[nf] = __builtin_amdgcn_mfma_f32_16x16x32_bf16(ah, bh[nf], acc2[nf], 0, 0, 0);
            acc2[nf] = __builtin_amdgcn_mfma_f32_16x16x32_bf16(ah, bl[nf], acc2[nf], 0, 0, 0);
            acc2[nf] = __builtin_amdgcn_mfma_f32_16x16x32_bf16(al, bh[nf], acc2[nf], 0, 0, 0);
        }
    }

    // ---------------- partial dot with Wf -> ws ----------------------------
    float b2c[2], wfc[2];
#pragma unroll
    for (int nf = 0; nf < 2; ++nf) {
        int col = ncb + nf * 16 + l15;
        b2c[nf] = b2[col];
        wfc[nf] = Wf[col];
    }
#pragma unroll
    for (int r = 0; r < 4; ++r) {
        float s = fmaxf(acc2[0][r] + b2c[0], 0.f) * wfc[0]
                + fmaxf(acc2[1][r] + b2c[1], 0.f) * wfc[1];
        s += __shfl_xor(s, 1);
        s += __shfl_xor(s, 2);
        s += __shfl_xor(s, 4);
        s += __shfl_xor(s, 8);
        if (l15 == 0)
            part[(size_t)(sl * 4 + wv) * NB + b0 + l4 * 4 + r] = s;
    }
}

// ---------------------------------------------------------------------------
// Finisher: out[b] = bf + sum of 16 partials. Single writer per output.
// ---------------------------------------------------------------------------
__global__ __launch_bounds__(256) void k_fin(const float* __restrict__ part,
                                             const float* __restrict__ bfp,
                                             float* __restrict__ out) {
    int b = blockIdx.x * 256 + threadIdx.x;
    float s = bfp[0];
#pragma unroll
    for (int i = 0; i < 16; ++i) s += part[(size_t)i * NB + b];
    out[b] = s;
}

extern "C" void kernel_launch(void* const* d_in, const int* in_sizes, int n_in,
                              void* d_out, int out_size, void* d_ws, size_t ws_size,
                              hipStream_t stream) {
    const float* obs = (const float*)d_in[0];
    const float* act = (const float*)d_in[1];
    const float* w0  = (const float*)d_in[2];
    const float* W1  = (const float*)d_in[3];
    const float* b1  = (const float*)d_in[4];
    const float* W2  = (const float*)d_in[5];
    const float* b2  = (const float*)d_in[6];
    const float* Wf  = (const float*)d_in[7];
    const float* bf  = (const float*)d_in[8];
    const int* adj   = (const int*)d_in[9];
    const int* tt    = (const int*)d_in[10];

    float* out = (float*)d_out;               // [0:NB) symbolic_val, [NB:) next_state
    float* outn = out + NB;

    char* base = (char*)d_ws;
    float* M    = (float*)base;                               // 64 KB
    short* nxtH = (short*)(base + (1u << 16));                // 1 MB
    short* nxtL = (short*)(base + (1u << 16) + (1u << 20));
    char* p = base + (1u << 16) + (2u << 20);
    short* W1pH = (short*)p;  p += (size_t)HH * ZZ * 2;       // 128 KB each
    short* W1pL = (short*)p;  p += (size_t)HH * ZZ * 2;
    short* W2pH = (short*)p;  p += (size_t)HH * HH * 2;       // 512 KB each
    short* W2pL = (short*)p;  p += (size_t)HH * HH * 2;
    float* part = (float*)p;                                  // 16*NB*4 = 256 KB

    k_prep<<<81, 256, 0, stream>>>(W1, W2, adj, tt, w0,
                                   W1pH, W1pL, W2pH, W2pL, M);
    k_next<<<NB / 2, 256, 0, stream>>>(obs, act, M, w0, outn, nxtH, nxtL);
    k_mlp<<<1024, 256, 0, stream>>>(nxtH, nxtL, W1pH, W1pL, W2pH, W2pL,
                                    b1, b2, Wf, part);
    k_fin<<<NB / 256, 256, 0, stream>>>(part, bf, out);
}